// Round 1
// baseline (517.033 us; speedup 1.0000x reference)
//
#include <hip/hip_runtime.h>
#include <hip/hip_bf16.h>

typedef short short8 __attribute__((ext_vector_type(8)));
typedef float f32x4 __attribute__((ext_vector_type(4)));
typedef unsigned short ushort_t;

__device__ __forceinline__ ushort_t f2bf(float f) {
    unsigned u = __builtin_bit_cast(unsigned, f);
    unsigned r = (u + 0x7FFFu + ((u >> 16) & 1u)) >> 16;
    return (ushort_t)r;
}

// -------------------------------------------------------------------------
// K1: per (n, row h): stage x[n][:, h, :] as bf16 [256px][64c] in LDS
// (XOR-swizzled), (a) write NHWC bf16 x_t, (b) attention dot via MFMA:
// s[n][d] += sum_px relu(att_w1[d,:]·x[:,px] + b1[d])
// -------------------------------------------------------------------------
__global__ __launch_bounds__(256) void dc_k1_stage_attn(
    const float* __restrict__ x, const float* __restrict__ w1,
    const float* __restrict__ b1, float* __restrict__ s_glob,
    ushort_t* __restrict__ x_t)
{
    __shared__ unsigned xt32[256 * 32];   // 256 px * 64c bf16 (32 dwords/px), swizzled
    __shared__ ushort_t w1s[16 * 64];
    __shared__ float sacc[16];

    const int n = blockIdx.y, h = blockIdx.x, t = threadIdx.x;
    if (t < 16) sacc[t] = 0.f;
#pragma unroll
    for (int q = 0; q < 4; ++q) { int idx = q * 256 + t; w1s[idx] = f2bf(w1[idx]); }

    const float* xr = x + ((size_t)n * 64) * 65536 + (size_t)h * 256;
    const int sw = (t & 7) << 2;  // dword-index XOR swizzle (bits 2-4)
    for (int cp = 0; cp < 32; ++cp) {
        float a = xr[(size_t)(2 * cp) * 65536 + t];
        float b = xr[(size_t)(2 * cp + 1) * 65536 + t];
        xt32[(t * 32 + cp) ^ sw] = (unsigned)f2bf(a) | ((unsigned)f2bf(b) << 16);
    }
    __syncthreads();

    const int lane = t & 63, wv = t >> 6, l15 = lane & 15, lg = lane >> 4;
    const short8* xt8 = reinterpret_cast<const short8*>(xt32);
    const short8* w18 = reinterpret_cast<const short8*>(w1s);

    // A-fragments: A[d=l15][c=lg*8+e] (K=32 halves)
    short8 a0 = w18[l15 * 8 + lg];
    short8 a1 = w18[l15 * 8 + 4 + lg];
    float b1v[4];
#pragma unroll
    for (int r = 0; r < 4; ++r) b1v[r] = b1[lg * 4 + r];

    float rs[4] = {0.f, 0.f, 0.f, 0.f};
#pragma unroll
    for (int q = 0; q < 4; ++q) {
        int pf = wv * 4 + q;
        int px = pf * 16 + l15;
        int pb = px * 8, ps = px & 7;
        short8 bb0 = xt8[pb + (lg ^ ps)];
        short8 bb1 = xt8[pb + ((4 + lg) ^ ps)];
        f32x4 hacc = {0.f, 0.f, 0.f, 0.f};
        hacc = __builtin_amdgcn_mfma_f32_16x16x32_bf16(a0, bb0, hacc, 0, 0, 0);
        hacc = __builtin_amdgcn_mfma_f32_16x16x32_bf16(a1, bb1, hacc, 0, 0, 0);
#pragma unroll
        for (int r = 0; r < 4; ++r) rs[r] += fmaxf(hacc[r] + b1v[r], 0.f);
    }
#pragma unroll
    for (int off = 1; off < 16; off <<= 1)
#pragma unroll
        for (int r = 0; r < 4; ++r) rs[r] += __shfl_xor(rs[r], off);
    if (l15 == 0) {
#pragma unroll
        for (int r = 0; r < 4; ++r) atomicAdd(&sacc[lg * 4 + r], rs[r]);
    }
    __syncthreads();
    if (t < 16) atomicAdd(&s_glob[n * 16 + t], sacc[t]);

    // write-out NHWC bf16 (de-swizzled reads, fully coalesced 1KB/wave stores)
    ushort_t* xo = x_t + (((size_t)n * 256 + h) * 256) * 64;
    const int cb = t & 7, pxr = t >> 3;
#pragma unroll
    for (int rr = 0; rr < 8; ++rr) {
        int px = rr * 32 + pxr;
        short8 v = xt8[px * 8 + (cb ^ (px & 7))];
        *reinterpret_cast<short8*>(xo + (size_t)px * 64 + cb * 8) = v;
    }
}

// -------------------------------------------------------------------------
// K2a: s -> pooled -> softmax(pi) ; aggregate bias b_agg[n][o]
// -------------------------------------------------------------------------
__global__ void dc_k2a_softmax_bias(
    const float* __restrict__ s_glob, const float* __restrict__ w2,
    const float* __restrict__ b2, const float* __restrict__ b_bank,
    float* __restrict__ pi, float* __restrict__ b_agg)
{
    __shared__ float piL[16][4];
    const int t = threadIdx.x;
    if (t < 16) {
        int n = t;
        float z[4];
#pragma unroll
        for (int e = 0; e < 4; ++e) {
            float p = 0.f;
            for (int d = 0; d < 16; ++d) p += w2[e * 16 + d] * s_glob[n * 16 + d];
            z[e] = (b2[e] + p * (1.f / 65536.f)) * (1.f / 30.f);
        }
        float m = fmaxf(fmaxf(z[0], z[1]), fmaxf(z[2], z[3]));
        float ex[4], sum = 0.f;
#pragma unroll
        for (int e = 0; e < 4; ++e) { ex[e] = expf(z[e] - m); sum += ex[e]; }
        float inv = 1.f / sum;
#pragma unroll
        for (int e = 0; e < 4; ++e) { float v = ex[e] * inv; pi[n * 4 + e] = v; piL[n][e] = v; }
    }
    __syncthreads();
    for (int r = 0; r < 16; ++r) {
        float v = 0.f;
#pragma unroll
        for (int kw = 0; kw < 4; ++kw) v += piL[r][kw] * b_bank[t * 4 + kw];
        b_agg[r * 64 + t] = v;
    }
}

// -------------------------------------------------------------------------
// K2b: aggregate weights -> A[n][o][ij*64+c] bf16 (MFMA-ready layout)
// -------------------------------------------------------------------------
__global__ void dc_k2b_aggw(const float* __restrict__ w_bank,
                            const float* __restrict__ pi,
                            ushort_t* __restrict__ A_agg)
{
    __shared__ float lw[2304];  // one o-row: [4 kw][64 c][9 ij]
    const int o = blockIdx.x, n = blockIdx.y, t = threadIdx.x;  // 64 threads
    const float* wrow = w_bank + (size_t)o * 2304;
    for (int rr = 0; rr < 36; ++rr) lw[rr * 64 + t] = wrow[rr * 64 + t];
    float p0 = pi[n * 4 + 0], p1 = pi[n * 4 + 1], p2 = pi[n * 4 + 2], p3 = pi[n * 4 + 3];
    __syncthreads();
    const int c = t;
    ushort_t* Aout = A_agg + ((size_t)n * 64 + o) * 576;
#pragma unroll
    for (int ij = 0; ij < 9; ++ij) {
        float v = p0 * lw[0 * 576 + c * 9 + ij] + p1 * lw[1 * 576 + c * 9 + ij]
                + p2 * lw[2 * 576 + c * 9 + ij] + p3 * lw[3 * 576 + c * 9 + ij];
        Aout[ij * 64 + c] = f2bf(v);
    }
}

// -------------------------------------------------------------------------
// K3: implicit-GEMM conv. Block = (n, h, 128-px half-row). 4 waves, each:
// M=64 (all Co), N=32 px. K=576 = 9 kernel-pos x 64 ch. bf16 MFMA 16x16x32.
// -------------------------------------------------------------------------
__global__ __launch_bounds__(256) void dc_k3_conv(
    const ushort_t* __restrict__ x_t, const ushort_t* __restrict__ A_agg,
    const float* __restrict__ b_agg, float* __restrict__ out)
{
    // XCD-chunked swizzle: 8192 blocks, 8 XCDs -> each XCD gets 1024
    // consecutive tiles (~2 samples) for L2 locality.
    int bid = blockIdx.x;
    int nb = (bid & 7) * 1024 + (bid >> 3);
    const int n = nb >> 9;
    const int tile = nb & 511;
    const int h = tile >> 1;
    const int w0 = (tile & 1) << 7;

    const int t = threadIdx.x, lane = t & 63, wv = t >> 6;
    const int l15 = lane & 15, lg = lane >> 4;
    const int pxw = w0 + wv * 32;

    const ushort_t* An = A_agg + (size_t)n * 64 * 576;
    const ushort_t* xtn = x_t + (size_t)n * 256 * 256 * 64;

    f32x4 acc[4][2] = {};

#pragma unroll
    for (int ij = 0; ij < 9; ++ij) {
        const int hh = h + ij / 3 - 1;
        const int jo = ij % 3 - 1;
        const bool hok = (unsigned)hh < 256u;
#pragma unroll
        for (int cc = 0; cc < 2; ++cc) {
            const int kbase = ij * 64 + cc * 32;
            short8 af[4];
#pragma unroll
            for (int mf = 0; mf < 4; ++mf)
                af[mf] = *reinterpret_cast<const short8*>(
                    An + (size_t)(mf * 16 + l15) * 576 + kbase + lg * 8);
            short8 bf[2];
#pragma unroll
            for (int nf = 0; nf < 2; ++nf) {
                int col = pxw + nf * 16 + l15 + jo;
                bool ok = hok && ((unsigned)col < 256u);
                short8 v = {0, 0, 0, 0, 0, 0, 0, 0};
                if (ok)
                    v = *reinterpret_cast<const short8*>(
                        xtn + ((size_t)hh * 256 + col) * 64 + cc * 32 + lg * 8);
                bf[nf] = v;
            }
#pragma unroll
            for (int mf = 0; mf < 4; ++mf)
#pragma unroll
                for (int nf = 0; nf < 2; ++nf)
                    acc[mf][nf] = __builtin_amdgcn_mfma_f32_16x16x32_bf16(
                        af[mf], bf[nf], acc[mf][nf], 0, 0, 0);
        }
    }

    const float* bn = b_agg + n * 64;
    float bv[4][4];
#pragma unroll
    for (int mf = 0; mf < 4; ++mf)
#pragma unroll
        for (int r = 0; r < 4; ++r) bv[mf][r] = bn[mf * 16 + lg * 4 + r];

#pragma unroll
    for (int mf = 0; mf < 4; ++mf) {
#pragma unroll
        for (int nf = 0; nf < 2; ++nf) {
            const int col = pxw + nf * 16 + l15;
            const size_t base = ((size_t)(n * 64 + mf * 16 + lg * 4) << 16)
                                + (size_t)h * 256 + col;
#pragma unroll
            for (int r = 0; r < 4; ++r)
                out[base + ((size_t)r << 16)] = acc[mf][nf][r] + bv[mf][r];
        }
    }
}

// -------------------------------------------------------------------------
extern "C" void kernel_launch(void* const* d_in, const int* in_sizes, int n_in,
                              void* d_out, int out_size, void* d_ws, size_t ws_size,
                              hipStream_t stream) {
    const float* x      = (const float*)d_in[0];
    const float* w_bank = (const float*)d_in[1];
    const float* b_bank = (const float*)d_in[2];
    const float* att_w1 = (const float*)d_in[3];
    const float* att_b1 = (const float*)d_in[4];
    const float* att_w2 = (const float*)d_in[5];
    const float* att_b2 = (const float*)d_in[6];
    float* out = (float*)d_out;

    char* ws = (char*)d_ws;
    float*    s_glob = (float*)ws;                     // 1 KB
    float*    pi     = (float*)(ws + 1024);            // 256 B
    float*    b_agg  = (float*)(ws + 2048);            // 4 KB
    ushort_t* A_agg  = (ushort_t*)(ws + 8192);         // 1.125 MB
    ushort_t* x_t    = (ushort_t*)(ws + (2ull << 20)); // 134.2 MB (NHWC bf16)

    hipMemsetAsync(s_glob, 0, 16 * 16 * sizeof(float), stream);

    dc_k1_stage_attn<<<dim3(256, 16), 256, 0, stream>>>(x, att_w1, att_b1, s_glob, x_t);
    dc_k2a_softmax_bias<<<1, 64, 0, stream>>>(s_glob, att_w2, att_b2, b_bank, pi, b_agg);
    dc_k2b_aggw<<<dim3(64, 16), 64, 0, stream>>>(w_bank, pi, A_agg);
    dc_k3_conv<<<8192, 256, 0, stream>>>(x_t, A_agg, b_agg, out);
}

// Round 2
// 263.148 us; speedup vs baseline: 1.9648x; 1.9648x over previous
//
#include <hip/hip_runtime.h>
#include <hip/hip_bf16.h>

typedef short short8 __attribute__((ext_vector_type(8)));
typedef float f32x4 __attribute__((ext_vector_type(4)));
typedef unsigned short ushort_t;

#define AS1 __attribute__((address_space(1)))
#define AS3 __attribute__((address_space(3)))

__device__ __forceinline__ ushort_t f2bf(float f) {
    unsigned u = __builtin_bit_cast(unsigned, f);
    unsigned r = (u + 0x7FFFu + ((u >> 16) & 1u)) >> 16;
    return (ushort_t)r;
}

__device__ __forceinline__ void gload_lds16(const void* g, void* l) {
    __builtin_amdgcn_global_load_lds((const AS1 unsigned*)g, (AS3 unsigned*)l, 16, 0, 0);
}

// -------------------------------------------------------------------------
// K0: zero the top/bottom padded border rows of x_t [16][258][258][64]
// -------------------------------------------------------------------------
__global__ __launch_bounds__(256) void dc_k0_zeroborder(ushort_t* __restrict__ x_t)
{
    const int b = blockIdx.x, t = threadIdx.x;
    const int n = b >> 1, row = (b & 1) ? 257 : 0;
    short8 z = {0, 0, 0, 0, 0, 0, 0, 0};
    short8* p = reinterpret_cast<short8*>(x_t + (size_t)(n * 258 + row) * 258 * 64);
    for (int i = t; i < 2064; i += 256) p[i] = z;  // 258*64/8
}

// -------------------------------------------------------------------------
// K1: per (n, row h): stage x[n][:, h, :] as bf16 [256px][64c] in LDS
// (XOR-swizzled), (a) write padded-NHWC bf16 x_t (+ zero col borders),
// (b) attention dot via MFMA: s[n][d] += sum_px relu(w1[d,:]·x[:,px]+b1[d])
// -------------------------------------------------------------------------
__global__ __launch_bounds__(256) void dc_k1_stage_attn(
    const float* __restrict__ x, const float* __restrict__ w1,
    const float* __restrict__ b1, float* __restrict__ s_glob,
    ushort_t* __restrict__ x_t)
{
    __shared__ unsigned xt32[256 * 32];   // 256 px * 64c bf16, swizzled
    __shared__ ushort_t w1s[16 * 64];
    __shared__ float sacc[16];

    const int n = blockIdx.y, h = blockIdx.x, t = threadIdx.x;
    if (t < 16) sacc[t] = 0.f;
#pragma unroll
    for (int q = 0; q < 4; ++q) { int idx = q * 256 + t; w1s[idx] = f2bf(w1[idx]); }

    const float* xr = x + ((size_t)n * 64) * 65536 + (size_t)h * 256;
    const int sw = (t & 7) << 2;
    for (int cp = 0; cp < 32; ++cp) {
        float a = xr[(size_t)(2 * cp) * 65536 + t];
        float b = xr[(size_t)(2 * cp + 1) * 65536 + t];
        xt32[(t * 32 + cp) ^ sw] = (unsigned)f2bf(a) | ((unsigned)f2bf(b) << 16);
    }
    __syncthreads();

    const int lane = t & 63, wv = t >> 6, l15 = lane & 15, lg = lane >> 4;
    const short8* xt8 = reinterpret_cast<const short8*>(xt32);
    const short8* w18 = reinterpret_cast<const short8*>(w1s);

    short8 a0 = w18[l15 * 8 + lg];
    short8 a1 = w18[l15 * 8 + 4 + lg];
    float b1v[4];
#pragma unroll
    for (int r = 0; r < 4; ++r) b1v[r] = b1[lg * 4 + r];

    float rs[4] = {0.f, 0.f, 0.f, 0.f};
#pragma unroll
    for (int q = 0; q < 4; ++q) {
        int px = (wv * 4 + q) * 16 + l15;
        int pb = px * 8, ps = px & 7;
        short8 bb0 = xt8[pb + (lg ^ ps)];
        short8 bb1 = xt8[pb + ((4 + lg) ^ ps)];
        f32x4 hacc = {0.f, 0.f, 0.f, 0.f};
        hacc = __builtin_amdgcn_mfma_f32_16x16x32_bf16(a0, bb0, hacc, 0, 0, 0);
        hacc = __builtin_amdgcn_mfma_f32_16x16x32_bf16(a1, bb1, hacc, 0, 0, 0);
#pragma unroll
        for (int r = 0; r < 4; ++r) rs[r] += fmaxf(hacc[r] + b1v[r], 0.f);
    }
#pragma unroll
    for (int off = 1; off < 16; off <<= 1)
#pragma unroll
        for (int r = 0; r < 4; ++r) rs[r] += __shfl_xor(rs[r], off);
    if (l15 == 0) {
#pragma unroll
        for (int r = 0; r < 4; ++r) atomicAdd(&sacc[lg * 4 + r], rs[r]);
    }
    __syncthreads();
    if (t < 16) atomicAdd(&s_glob[n * 16 + t], sacc[t]);

    // write-out padded NHWC bf16 (interior cols 1..256 of padded row h+1)
    ushort_t* xo = x_t + (((size_t)n * 258 + h + 1) * 258 + 1) * 64;
    const int cb = t & 7, pxr = t >> 3;
#pragma unroll
    for (int rr = 0; rr < 8; ++rr) {
        int px = rr * 32 + pxr;
        short8 v = xt8[px * 8 + (cb ^ (px & 7))];
        *reinterpret_cast<short8*>(xo + (size_t)px * 64 + cb * 8) = v;
    }
    // zero the left/right padded columns of this row
    if (t < 16) {
        short8 z = {0, 0, 0, 0, 0, 0, 0, 0};
        size_t colbase = (((size_t)n * 258 + h + 1) * 258 + ((t < 8) ? 0 : 257)) * 64;
        reinterpret_cast<short8*>(x_t + colbase)[t & 7] = z;
    }
}

// -------------------------------------------------------------------------
// K2a: s -> pooled -> softmax(pi) ; aggregate bias b_agg[n][o]
// -------------------------------------------------------------------------
__global__ void dc_k2a_softmax_bias(
    const float* __restrict__ s_glob, const float* __restrict__ w2,
    const float* __restrict__ b2, const float* __restrict__ b_bank,
    float* __restrict__ pi, float* __restrict__ b_agg)
{
    __shared__ float piL[16][4];
    const int t = threadIdx.x;
    if (t < 16) {
        int n = t;
        float z[4];
#pragma unroll
        for (int e = 0; e < 4; ++e) {
            float p = 0.f;
            for (int d = 0; d < 16; ++d) p += w2[e * 16 + d] * s_glob[n * 16 + d];
            z[e] = (b2[e] + p * (1.f / 65536.f)) * (1.f / 30.f);
        }
        float m = fmaxf(fmaxf(z[0], z[1]), fmaxf(z[2], z[3]));
        float ex[4], sum = 0.f;
#pragma unroll
        for (int e = 0; e < 4; ++e) { ex[e] = expf(z[e] - m); sum += ex[e]; }
        float inv = 1.f / sum;
#pragma unroll
        for (int e = 0; e < 4; ++e) { float v = ex[e] * inv; pi[n * 4 + e] = v; piL[n][e] = v; }
    }
    __syncthreads();
    for (int r = 0; r < 16; ++r) {
        float v = 0.f;
#pragma unroll
        for (int kw = 0; kw < 4; ++kw) v += piL[r][kw] * b_bank[t * 4 + kw];
        b_agg[r * 64 + t] = v;
    }
}

// -------------------------------------------------------------------------
// K2b: aggregate weights -> fragment-major A_frag[n][ks=ij*2+cc][mf][lane][8]
// (so each wave A-load in K3 is one contiguous, coalesced 1KB load)
// -------------------------------------------------------------------------
__global__ void dc_k2b_aggw(const float* __restrict__ w_bank,
                            const float* __restrict__ pi,
                            ushort_t* __restrict__ A_frag)
{
    __shared__ float lw[2304];  // one o-row: [4 kw][64 c][9 ij]
    const int o = blockIdx.x, n = blockIdx.y, t = threadIdx.x;  // 64 threads
    const float* wrow = w_bank + (size_t)o * 2304;
    for (int rr = 0; rr < 36; ++rr) lw[rr * 64 + t] = wrow[rr * 64 + t];
    float p0 = pi[n * 4 + 0], p1 = pi[n * 4 + 1], p2 = pi[n * 4 + 2], p3 = pi[n * 4 + 3];
    __syncthreads();
    const int c = t;
    const int cc = c >> 5, lg = (c >> 3) & 3, e = c & 7;
    const int mf = o >> 4, l15 = o & 15;
    ushort_t* base = A_frag + (size_t)n * 18 * 4 * 64 * 8;
#pragma unroll
    for (int ij = 0; ij < 9; ++ij) {
        float v = p0 * lw[0 * 576 + c * 9 + ij] + p1 * lw[1 * 576 + c * 9 + ij]
                + p2 * lw[2 * 576 + c * 9 + ij] + p3 * lw[3 * 576 + c * 9 + ij];
        int ks = ij * 2 + cc;
        base[(((ks * 4 + mf) * 64) + (lg * 16 + l15)) * 8 + e] = f2bf(v);
    }
}

// -------------------------------------------------------------------------
// K3: implicit-GEMM conv. Block = (n, h, 128-px half-row), 4 waves.
// LDS-staged input tile [3 rows][136 cols][64 ch] bf16 via global_load_lds
// (pre-swizzled source + XOR-swizzled ds_read -> conflict-free b128).
// -------------------------------------------------------------------------
__global__ __launch_bounds__(256) void dc_k3_conv(
    const ushort_t* __restrict__ x_t, const ushort_t* __restrict__ A_frag,
    const float* __restrict__ b_agg, float* __restrict__ out)
{
    __shared__ char lds[3 * 17408];  // 52,224 B

    int bid = blockIdx.x;
    int nb = (bid & 7) * 1024 + (bid >> 3);   // XCD-chunked swizzle
    const int n = nb >> 9;
    const int tile = nb & 511;
    const int h = tile >> 1;
    const int w0 = (tile & 1) << 7;

    const int t = threadIdx.x, lane = t & 63, wv = t >> 6;
    const int l15 = lane & 15, lg = lane >> 4;

    // ---- stage 3 padded rows x 136 cols x 64ch (17 KB each) ----
    const char* srcb = (const char*)x_t;
#pragma unroll
    for (int r = 0; r < 3; ++r) {
        size_t rowoff = ((size_t)(n * 258 + h + r) * 258 + w0) * 128;
        for (int k = wv; k < 17; k += 4) {
            unsigned q = k * 1024 + lane * 16;
            unsigned so = q ^ (((q >> 7) & 7) << 4);   // source pre-swizzle
            gload_lds16(srcb + rowoff + so, lds + r * 17408 + k * 1024);
        }
    }
    asm volatile("s_waitcnt vmcnt(0)" ::: "memory");
    __syncthreads();

    const ushort_t* Af = A_frag + (size_t)n * 18 * 4 * 64 * 8;
    const int pxl = wv * 32;

    f32x4 acc[4][2] = {};

#pragma unroll
    for (int ij = 0; ij < 9; ++ij) {
        const int r = ij / 3, jo = ij % 3 - 1;
#pragma unroll
        for (int cc = 0; cc < 2; ++cc) {
            const int ks = ij * 2 + cc;
            short8 af[4];
#pragma unroll
            for (int mf = 0; mf < 4; ++mf)
                af[mf] = *reinterpret_cast<const short8*>(
                    Af + ((size_t)(ks * 4 + mf) * 64 + lane) * 8);
            short8 bf[2];
#pragma unroll
            for (int nf = 0; nf < 2; ++nf) {
                int colL = pxl + nf * 16 + l15 + jo + 1;
                unsigned off = ((unsigned)(r * 136 + colL) * 128 + cc * 64 + lg * 16)
                               ^ (unsigned)((colL & 7) << 4);
                bf[nf] = *reinterpret_cast<const short8*>(lds + off);
            }
#pragma unroll
            for (int mf = 0; mf < 4; ++mf)
#pragma unroll
                for (int nf = 0; nf < 2; ++nf)
                    acc[mf][nf] = __builtin_amdgcn_mfma_f32_16x16x32_bf16(
                        af[mf], bf[nf], acc[mf][nf], 0, 0, 0);
        }
    }

    const float* bn = b_agg + n * 64;
    float bv[4][4];
#pragma unroll
    for (int mf = 0; mf < 4; ++mf)
#pragma unroll
        for (int r = 0; r < 4; ++r) bv[mf][r] = bn[mf * 16 + lg * 4 + r];

#pragma unroll
    for (int mf = 0; mf < 4; ++mf) {
#pragma unroll
        for (int nf = 0; nf < 2; ++nf) {
            const int col = w0 + pxl + nf * 16 + l15;
            const size_t base = ((size_t)(n * 64 + mf * 16 + lg * 4) << 16)
                                + (size_t)h * 256 + col;
#pragma unroll
            for (int r = 0; r < 4; ++r)
                out[base + ((size_t)r << 16)] = acc[mf][nf][r] + bv[mf][r];
        }
    }
}

// -------------------------------------------------------------------------
extern "C" void kernel_launch(void* const* d_in, const int* in_sizes, int n_in,
                              void* d_out, int out_size, void* d_ws, size_t ws_size,
                              hipStream_t stream) {
    const float* x      = (const float*)d_in[0];
    const float* w_bank = (const float*)d_in[1];
    const float* b_bank = (const float*)d_in[2];
    const float* att_w1 = (const float*)d_in[3];
    const float* att_b1 = (const float*)d_in[4];
    const float* att_w2 = (const float*)d_in[5];
    const float* att_b2 = (const float*)d_in[6];
    float* out = (float*)d_out;

    char* ws = (char*)d_ws;
    float*    s_glob = (float*)ws;                     // 1 KB
    float*    pi     = (float*)(ws + 1024);            // 256 B
    float*    b_agg  = (float*)(ws + 2048);            // 4 KB
    ushort_t* A_frag = (ushort_t*)(ws + 8192);         // 1.125 MB
    ushort_t* x_t    = (ushort_t*)(ws + (2ull << 20)); // padded NHWC bf16, ~136.3 MB (+4KB slack)

    hipMemsetAsync(s_glob, 0, 16 * 16 * sizeof(float), stream);

    dc_k0_zeroborder<<<32, 256, 0, stream>>>(x_t);
    dc_k1_stage_attn<<<dim3(256, 16), 256, 0, stream>>>(x, att_w1, att_b1, s_glob, x_t);
    dc_k2a_softmax_bias<<<1, 64, 0, stream>>>(s_glob, att_w2, att_b2, b_bank, pi, b_agg);
    dc_k2b_aggw<<<dim3(64, 16), 64, 0, stream>>>(w_bank, pi, A_frag);
    dc_k3_conv<<<8192, 256, 0, stream>>>(x_t, A_frag, b_agg, out);
}

// Round 3
// 244.021 us; speedup vs baseline: 2.1188x; 1.0784x over previous
//
#include <hip/hip_runtime.h>
#include <hip/hip_bf16.h>

typedef short short8 __attribute__((ext_vector_type(8)));
typedef float f32x4 __attribute__((ext_vector_type(4)));
typedef unsigned short ushort_t;

#define AS1 __attribute__((address_space(1)))
#define AS3 __attribute__((address_space(3)))

__device__ __forceinline__ ushort_t f2bf(float f) {
    unsigned u = __builtin_bit_cast(unsigned, f);
    unsigned r = (u + 0x7FFFu + ((u >> 16) & 1u)) >> 16;
    return (ushort_t)r;
}

__device__ __forceinline__ void gload_lds16(const void* g, void* l) {
    __builtin_amdgcn_global_load_lds((const AS1 unsigned*)g, (AS3 unsigned*)l, 16, 0, 0);
}

// -------------------------------------------------------------------------
// K0: zero the top/bottom padded border rows of x_t [16][258][258][64]
// -------------------------------------------------------------------------
__global__ __launch_bounds__(256) void dc_k0_zeroborder(ushort_t* __restrict__ x_t)
{
    const int b = blockIdx.x, t = threadIdx.x;
    const int n = b >> 1, row = (b & 1) ? 257 : 0;
    short8 z = {0, 0, 0, 0, 0, 0, 0, 0};
    short8* p = reinterpret_cast<short8*>(x_t + (size_t)(n * 258 + row) * 258 * 64);
    for (int i = t; i < 2064; i += 256) p[i] = z;  // 258*64/8
}

// -------------------------------------------------------------------------
// K1: per (n, row h): stage x[n][:, h, :] as bf16 [256px][64c] in LDS
// (XOR-swizzled), (a) write padded-NHWC bf16 x_t (+ zero col borders),
// (b) attention dot via MFMA: s[n][d] += sum_px relu(w1[d,:]·x[:,px]+b1[d])
// -------------------------------------------------------------------------
__global__ __launch_bounds__(256) void dc_k1_stage_attn(
    const float* __restrict__ x, const float* __restrict__ w1,
    const float* __restrict__ b1, float* __restrict__ s_glob,
    ushort_t* __restrict__ x_t)
{
    __shared__ unsigned xt32[256 * 32];   // 256 px * 64c bf16, swizzled
    __shared__ ushort_t w1s[16 * 64];
    __shared__ float sacc[16];

    const int n = blockIdx.y, h = blockIdx.x, t = threadIdx.x;
    if (t < 16) sacc[t] = 0.f;
#pragma unroll
    for (int q = 0; q < 4; ++q) { int idx = q * 256 + t; w1s[idx] = f2bf(w1[idx]); }

    const float* xr = x + ((size_t)n * 64) * 65536 + (size_t)h * 256;
    const int sw = (t & 7) << 2;
    for (int cp = 0; cp < 32; ++cp) {
        float a = xr[(size_t)(2 * cp) * 65536 + t];
        float b = xr[(size_t)(2 * cp + 1) * 65536 + t];
        xt32[(t * 32 + cp) ^ sw] = (unsigned)f2bf(a) | ((unsigned)f2bf(b) << 16);
    }
    __syncthreads();

    const int lane = t & 63, wv = t >> 6, l15 = lane & 15, lg = lane >> 4;
    const short8* xt8 = reinterpret_cast<const short8*>(xt32);
    const short8* w18 = reinterpret_cast<const short8*>(w1s);

    short8 a0 = w18[l15 * 8 + lg];
    short8 a1 = w18[l15 * 8 + 4 + lg];
    float b1v[4];
#pragma unroll
    for (int r = 0; r < 4; ++r) b1v[r] = b1[lg * 4 + r];

    float rs[4] = {0.f, 0.f, 0.f, 0.f};
#pragma unroll
    for (int q = 0; q < 4; ++q) {
        int px = (wv * 4 + q) * 16 + l15;
        int pb = px * 8, ps = px & 7;
        short8 bb0 = xt8[pb + (lg ^ ps)];
        short8 bb1 = xt8[pb + ((4 + lg) ^ ps)];
        f32x4 hacc = {0.f, 0.f, 0.f, 0.f};
        hacc = __builtin_amdgcn_mfma_f32_16x16x32_bf16(a0, bb0, hacc, 0, 0, 0);
        hacc = __builtin_amdgcn_mfma_f32_16x16x32_bf16(a1, bb1, hacc, 0, 0, 0);
#pragma unroll
        for (int r = 0; r < 4; ++r) rs[r] += fmaxf(hacc[r] + b1v[r], 0.f);
    }
#pragma unroll
    for (int off = 1; off < 16; off <<= 1)
#pragma unroll
        for (int r = 0; r < 4; ++r) rs[r] += __shfl_xor(rs[r], off);
    if (l15 == 0) {
#pragma unroll
        for (int r = 0; r < 4; ++r) atomicAdd(&sacc[lg * 4 + r], rs[r]);
    }
    __syncthreads();
    if (t < 16) atomicAdd(&s_glob[n * 16 + t], sacc[t]);

    // write-out padded NHWC bf16 (interior cols 1..256 of padded row h+1)
    ushort_t* xo = x_t + (((size_t)n * 258 + h + 1) * 258 + 1) * 64;
    const int cb = t & 7, pxr = t >> 3;
#pragma unroll
    for (int rr = 0; rr < 8; ++rr) {
        int px = rr * 32 + pxr;
        short8 v = xt8[px * 8 + (cb ^ (px & 7))];
        *reinterpret_cast<short8*>(xo + (size_t)px * 64 + cb * 8) = v;
    }
    // zero the left/right padded columns of this row
    if (t < 16) {
        short8 z = {0, 0, 0, 0, 0, 0, 0, 0};
        size_t colbase = (((size_t)n * 258 + h + 1) * 258 + ((t < 8) ? 0 : 257)) * 64;
        reinterpret_cast<short8*>(x_t + colbase)[t & 7] = z;
    }
}

// -------------------------------------------------------------------------
// K2a: s -> pooled -> softmax(pi) ; aggregate bias b_agg[n][o]
// -------------------------------------------------------------------------
__global__ void dc_k2a_softmax_bias(
    const float* __restrict__ s_glob, const float* __restrict__ w2,
    const float* __restrict__ b2, const float* __restrict__ b_bank,
    float* __restrict__ pi, float* __restrict__ b_agg)
{
    __shared__ float piL[16][4];
    const int t = threadIdx.x;
    if (t < 16) {
        int n = t;
        float z[4];
#pragma unroll
        for (int e = 0; e < 4; ++e) {
            float p = 0.f;
            for (int d = 0; d < 16; ++d) p += w2[e * 16 + d] * s_glob[n * 16 + d];
            z[e] = (b2[e] + p * (1.f / 65536.f)) * (1.f / 30.f);
        }
        float m = fmaxf(fmaxf(z[0], z[1]), fmaxf(z[2], z[3]));
        float ex[4], sum = 0.f;
#pragma unroll
        for (int e = 0; e < 4; ++e) { ex[e] = expf(z[e] - m); sum += ex[e]; }
        float inv = 1.f / sum;
#pragma unroll
        for (int e = 0; e < 4; ++e) { float v = ex[e] * inv; pi[n * 4 + e] = v; piL[n][e] = v; }
    }
    __syncthreads();
    for (int r = 0; r < 16; ++r) {
        float v = 0.f;
#pragma unroll
        for (int kw = 0; kw < 4; ++kw) v += piL[r][kw] * b_bank[t * 4 + kw];
        b_agg[r * 64 + t] = v;
    }
}

// -------------------------------------------------------------------------
// K2b: aggregate weights -> fragment-major A_frag[n][ks=ij*2+cc][mf][lane][8]
// (so each wave A-load in K3 is one contiguous, coalesced 1KB load)
// -------------------------------------------------------------------------
__global__ void dc_k2b_aggw(const float* __restrict__ w_bank,
                            const float* __restrict__ pi,
                            ushort_t* __restrict__ A_frag)
{
    __shared__ float lw[2304];  // one o-row: [4 kw][64 c][9 ij]
    const int o = blockIdx.x, n = blockIdx.y, t = threadIdx.x;  // 64 threads
    const float* wrow = w_bank + (size_t)o * 2304;
    for (int rr = 0; rr < 36; ++rr) lw[rr * 64 + t] = wrow[rr * 64 + t];
    float p0 = pi[n * 4 + 0], p1 = pi[n * 4 + 1], p2 = pi[n * 4 + 2], p3 = pi[n * 4 + 3];
    __syncthreads();
    const int c = t;
    const int cc = c >> 5, lg = (c >> 3) & 3, e = c & 7;
    const int mf = o >> 4, l15 = o & 15;
    ushort_t* base = A_frag + (size_t)n * 18 * 4 * 64 * 8;
#pragma unroll
    for (int ij = 0; ij < 9; ++ij) {
        float v = p0 * lw[0 * 576 + c * 9 + ij] + p1 * lw[1 * 576 + c * 9 + ij]
                + p2 * lw[2 * 576 + c * 9 + ij] + p3 * lw[3 * 576 + c * 9 + ij];
        int ks = ij * 2 + cc;
        base[(((ks * 4 + mf) * 64) + (lg * 16 + l15)) * 8 + e] = f2bf(v);
    }
}

// -------------------------------------------------------------------------
// K3: implicit-GEMM conv, 2 output rows per block.
// Block = (n, h0=2*h2, 128-px half-row), 4 waves; wave = 64 Co x 32 px x 2 rows.
// LDS: 4 padded input rows x 136 cols x 64 ch bf16 (global_load_lds,
// pre-swizzled source + XOR-swizzled ds_read = conflict-free b128).
// A-fragments: global (L2-hot), software-pipelined 1-deep double buffer.
// B-fragments: 4 row-frags loaded once per (jo,cc), shared across o=0/1.
// -------------------------------------------------------------------------
__global__ __launch_bounds__(256) void dc_k3_conv(
    const ushort_t* __restrict__ x_t, const ushort_t* __restrict__ A_frag,
    const float* __restrict__ b_agg, float* __restrict__ out)
{
    __shared__ char lds[4 * 17408];  // 69,632 B -> 2 blocks/CU

    int bid = blockIdx.x;
    int nb = (bid & 7) * 512 + (bid >> 3);   // XCD-chunked swizzle (4096 % 8 == 0)
    const int n = nb >> 8;
    const int tile = nb & 255;
    const int h0 = (tile >> 1) << 1;         // output rows h0, h0+1
    const int w0 = (tile & 1) << 7;

    const int t = threadIdx.x, lane = t & 63, wv = t >> 6;
    const int l15 = lane & 15, lg = lane >> 4;

    // ---- stage 4 padded rows x 136 cols x 64ch (17 KB each) ----
    const char* srcb = (const char*)x_t;
#pragma unroll
    for (int r = 0; r < 4; ++r) {
        size_t rowoff = ((size_t)(n * 258 + h0 + r) * 258 + w0) * 128;
        for (int k = wv; k < 17; k += 4) {
            unsigned q = k * 1024 + lane * 16;
            unsigned so = q ^ (((q >> 7) & 7) << 4);   // source pre-swizzle
            gload_lds16(srcb + rowoff + so, lds + r * 17408 + k * 1024);
        }
    }
    asm volatile("s_waitcnt vmcnt(0)" ::: "memory");
    __syncthreads();

    const ushort_t* Aln = A_frag + (size_t)n * 36864 + (size_t)lane * 8;
    const int pxl = wv * 32;

    f32x4 acc[4][2][2] = {};
    short8 bf[4][2];
    short8 afA[4], afB[4];

    // preload s=0 (jc=0 -> jcol=0, cc=0; ir=0 -> ij=0, ks=0)
#pragma unroll
    for (int mf = 0; mf < 4; ++mf)
        afA[mf] = *reinterpret_cast<const short8*>(Aln + mf * 512);

#pragma unroll
    for (int s = 0; s < 18; ++s) {
        const int jc = s / 3, ir = s % 3;
        const int jcol = jc >> 1, cc = jc & 1;
        if (ir == 0) {
            const int jo = jcol - 1;
#pragma unroll
            for (int r = 0; r < 4; ++r)
#pragma unroll
                for (int nf = 0; nf < 2; ++nf) {
                    int colL = pxl + nf * 16 + l15 + jo + 1;
                    unsigned off = ((unsigned)(r * 136 + colL) * 128 + cc * 64 + lg * 16)
                                   ^ (unsigned)((colL & 7) << 4);
                    bf[r][nf] = *reinterpret_cast<const short8*>(lds + off);
                }
        }
        short8* cur = (s & 1) ? afB : afA;
        short8* nxt = (s & 1) ? afA : afB;
        if (s < 17) {
            const int s1 = s + 1;
            const int jc1 = s1 / 3, ir1 = s1 % 3;
            const int ks1 = (ir1 * 3 + (jc1 >> 1)) * 2 + (jc1 & 1);
#pragma unroll
            for (int mf = 0; mf < 4; ++mf)
                nxt[mf] = *reinterpret_cast<const short8*>(Aln + (ks1 * 4 + mf) * 512);
        }
#pragma unroll
        for (int mf = 0; mf < 4; ++mf)
#pragma unroll
            for (int nf = 0; nf < 2; ++nf)
#pragma unroll
                for (int o = 0; o < 2; ++o)
                    acc[mf][nf][o] = __builtin_amdgcn_mfma_f32_16x16x32_bf16(
                        cur[mf], bf[ir + o][nf], acc[mf][nf][o], 0, 0, 0);
    }

    const float* bn = b_agg + n * 64;
#pragma unroll
    for (int mf = 0; mf < 4; ++mf) {
#pragma unroll
        for (int r = 0; r < 4; ++r) {
            const float bval = bn[mf * 16 + lg * 4 + r];
#pragma unroll
            for (int o = 0; o < 2; ++o)
#pragma unroll
                for (int nf = 0; nf < 2; ++nf) {
                    const int col = w0 + pxl + nf * 16 + l15;
                    const size_t base = ((size_t)(n * 64 + mf * 16 + lg * 4 + r) << 16)
                                        + (size_t)(h0 + o) * 256 + col;
                    out[base] = acc[mf][nf][o][r] + bval;
                }
        }
    }
}

// -------------------------------------------------------------------------
extern "C" void kernel_launch(void* const* d_in, const int* in_sizes, int n_in,
                              void* d_out, int out_size, void* d_ws, size_t ws_size,
                              hipStream_t stream) {
    const float* x      = (const float*)d_in[0];
    const float* w_bank = (const float*)d_in[1];
    const float* b_bank = (const float*)d_in[2];
    const float* att_w1 = (const float*)d_in[3];
    const float* att_b1 = (const float*)d_in[4];
    const float* att_w2 = (const float*)d_in[5];
    const float* att_b2 = (const float*)d_in[6];
    float* out = (float*)d_out;

    char* ws = (char*)d_ws;
    float*    s_glob = (float*)ws;                     // 1 KB
    float*    pi     = (float*)(ws + 1024);            // 256 B
    float*    b_agg  = (float*)(ws + 2048);            // 4 KB
    ushort_t* A_frag = (ushort_t*)(ws + 8192);         // 1.125 MB
    ushort_t* x_t    = (ushort_t*)(ws + (2ull << 20)); // padded NHWC bf16, ~136.3 MB

    hipMemsetAsync(s_glob, 0, 16 * 16 * sizeof(float), stream);

    dc_k0_zeroborder<<<32, 256, 0, stream>>>(x_t);
    dc_k1_stage_attn<<<dim3(256, 16), 256, 0, stream>>>(x, att_w1, att_b1, s_glob, x_t);
    dc_k2a_softmax_bias<<<1, 64, 0, stream>>>(s_glob, att_w2, att_b2, b_bank, pi, b_agg);
    dc_k2b_aggw<<<dim3(64, 16), 64, 0, stream>>>(w_bank, pi, A_frag);
    dc_k3_conv<<<4096, 256, 0, stream>>>(x_t, A_frag, b_agg, out);
}